// Round 1
// 293.213 us; speedup vs baseline: 1.0312x; 1.0312x over previous
//
#include <hip/hip_runtime.h>
#include <hip/hip_fp16.h>

// out = segment_sum(x[edge_col] * edge_vals[:,None], edge_row) @ W
// N=100000, E=1600000, D=128.
//
// R6: (A·X)·W -> A·(X·W). GEMM first into fp16 y, then coarse counting-sort
// + fused per-bucket LDS-sort + register-gather kernel.
// R7 (this round): bucket_agg was latency-bound at 30% occupancy (grid 782
// blocks = 3/CU was the cap; VALU 25%, HBM 33%). Split coarse buckets
// 128 rows -> 64 rows: CB 782 -> 1563 blocks (~6.1/CU), CAP 3072 -> 2048
// (LDS 26.1 KB -> 17.2 KB, wave-capped at 8 blocks/CU). Scan reworked to
// 2 elems/thread for 1563 counters.

#define N_NODES 100000
#define N_EDGES 1600000
#define DIM     128
#define BROWS   64           // rows per coarse bucket
#define CB      1563         // coarse buckets = ceil(N/64)
#define CAP     2048         // LDS sort capacity per chunk (mean bucket=1024, sigma~32)

// ---- workspace layout (bytes) ----
// y     @ 0        : N*128 fp16 = 25.6 MB
// ccnt  @ 25600000 : 1563 u32
// cstart@ 25606400 : 1564 u32
// ccur  @ 25612800 : 1563 u32
// ebuf1 @ 25619200 : E uint2 {rl<<17|col, val_bits} = 12.8 MB   (peak 38.4 MB)
#define OFF_CCNT   25600000
#define OFF_CSTART 25606400
#define OFF_CCUR   25612800
#define OFF_EBUF1  25619200

// ---------------------------------------------------------------- GEMM x@W -> y (fp16)
__global__ __launch_bounds__(256) void gemm_xw_kernel(
    const float* __restrict__ x,
    const float* __restrict__ W,
    __half*      __restrict__ y)
{
    __shared__ float As[32 * 32];
    __shared__ float Ws[32 * 128];

    const int t    = threadIdx.x;
    const int row0 = blockIdx.x * 32;          // 3125 blocks exact
    const int r0   = (t >> 5) * 4;
    const int c0   = (t & 31) * 4;

    float acc[4][4];
#pragma unroll
    for (int i = 0; i < 4; ++i)
#pragma unroll
        for (int j = 0; j < 4; ++j) acc[i][j] = 0.f;

    for (int k0 = 0; k0 < 128; k0 += 32) {
        {
            int r  = t >> 3;
            int kp = t & 7;
            float4 a = *(const float4*)(x + (size_t)(row0 + r) * 128 + k0 + kp * 4);
            *(float4*)(As + r * 32 + kp * 4) = a;
        }
        {
            const float4* Wg = (const float4*)(W + (size_t)k0 * 128);
            float4* Wl = (float4*)Ws;
#pragma unroll
            for (int i = 0; i < 4; ++i) Wl[t + 256 * i] = Wg[t + 256 * i];
        }
        __syncthreads();

#pragma unroll
        for (int kk = 0; kk < 32; ++kk) {
            float4 w = *(const float4*)(Ws + kk * 128 + c0);
            float a0 = As[(r0 + 0) * 32 + kk];
            float a1 = As[(r0 + 1) * 32 + kk];
            float a2 = As[(r0 + 2) * 32 + kk];
            float a3 = As[(r0 + 3) * 32 + kk];
            acc[0][0] += a0 * w.x; acc[0][1] += a0 * w.y; acc[0][2] += a0 * w.z; acc[0][3] += a0 * w.w;
            acc[1][0] += a1 * w.x; acc[1][1] += a1 * w.y; acc[1][2] += a1 * w.z; acc[1][3] += a1 * w.w;
            acc[2][0] += a2 * w.x; acc[2][1] += a2 * w.y; acc[2][2] += a2 * w.z; acc[2][3] += a2 * w.w;
            acc[3][0] += a3 * w.x; acc[3][1] += a3 * w.y; acc[3][2] += a3 * w.z; acc[3][3] += a3 * w.w;
        }
        __syncthreads();
    }

#pragma unroll
    for (int i = 0; i < 4; ++i) {
        __half2 p0 = __floats2half2_rn(acc[i][0], acc[i][1]);
        __half2 p1 = __floats2half2_rn(acc[i][2], acc[i][3]);
        uint2 w;
        w.x = *(const unsigned*)&p0;
        w.y = *(const unsigned*)&p1;
        *(uint2*)(y + (size_t)(row0 + r0 + i) * 128 + c0) = w;
    }
}

// ---------------------------------------------------------------- zero coarse cnt
__global__ __launch_bounds__(256) void zero_ccnt_kernel(unsigned* ccnt) {
    int i = blockIdx.x * 256 + threadIdx.x;
    if (i < CB) ccnt[i] = 0u;
}

// ---------------------------------------------------------------- coarse hist
__global__ __launch_bounds__(256) void coarse_hist_kernel(
    const int* __restrict__ erow, unsigned* __restrict__ ccnt)
{
    __shared__ unsigned lh[CB];
    const int t = threadIdx.x;
    const unsigned e0 = blockIdx.x * 8192u;      // 196 blocks
    for (int i = t; i < CB; i += 256) lh[i] = 0u;
    __syncthreads();
#pragma unroll 4
    for (int k = 0; k < 32; ++k) {
        unsigned e = e0 + k * 256u + t;
        if (e < N_EDGES) atomicAdd(&lh[(unsigned)erow[e] >> 6], 1u);
    }
    __syncthreads();
    for (int i = t; i < CB; i += 256) {
        unsigned h = lh[i];
        if (h) atomicAdd(&ccnt[i], h);
    }
}

// ---------------------------------------------------------------- coarse scan
// single block of 1024, 2 counters/thread: exclusive scan of 1563 counters
// -> cstart[0..1563], ccur
__global__ __launch_bounds__(1024) void coarse_scan_kernel(
    const unsigned* __restrict__ ccnt,
    unsigned* __restrict__ cstart,
    unsigned* __restrict__ ccur)
{
    __shared__ unsigned wsum[16];
    const int t  = threadIdx.x;
    const int i0 = 2 * t;
    unsigned a  = (i0     < CB) ? ccnt[i0]     : 0u;
    unsigned bb = (i0 + 1 < CB) ? ccnt[i0 + 1] : 0u;
    unsigned s  = a + bb;
    unsigned inc = s;
#pragma unroll
    for (int d = 1; d < 64; d <<= 1) {
        unsigned o = __shfl_up(inc, d);
        if ((t & 63) >= d) inc += o;
    }
    if ((t & 63) == 63) wsum[t >> 6] = inc;
    __syncthreads();
    if (t == 0) {
        unsigned run = 0;
#pragma unroll
        for (int w = 0; w < 16; ++w) { unsigned sw = wsum[w]; wsum[w] = run; run += sw; }
        cstart[CB] = run;            // == E
    }
    __syncthreads();
    unsigned excl = inc - s + wsum[t >> 6];
    if (i0 < CB)     { cstart[i0]     = excl;     ccur[i0]     = excl;     }
    if (i0 + 1 < CB) { cstart[i0 + 1] = excl + a; ccur[i0 + 1] = excl + a; }
}

// ---------------------------------------------------------------- partition
// LDS hist over 1563 buckets per 8192-edge chunk, reserve, scatter runs.
// record: {rowLocal(6b)<<17 | col(17b), val_bits}
__global__ __launch_bounds__(256) void partition_kernel(
    const int*   __restrict__ erow,
    const int*   __restrict__ ecol,
    const float* __restrict__ eval,
    unsigned*    __restrict__ ccur,
    uint2*       __restrict__ ebuf1)
{
    __shared__ unsigned hist[CB];
    __shared__ unsigned gbase[CB];
    const int t = threadIdx.x;
    const unsigned e0 = blockIdx.x * 8192u;      // 196 blocks

    for (int i = t; i < CB; i += 256) hist[i] = 0u;
    __syncthreads();

#pragma unroll 4
    for (int k = 0; k < 32; ++k) {
        unsigned e = e0 + k * 256u + t;
        if (e < N_EDGES) atomicAdd(&hist[(unsigned)erow[e] >> 6], 1u);
    }
    __syncthreads();

    for (int i = t; i < CB; i += 256) {
        unsigned h = hist[i];
        gbase[i] = h ? atomicAdd(&ccur[i], h) : 0u;
        hist[i] = 0u;                            // reuse as local rank counter
    }
    __syncthreads();

#pragma unroll 4
    for (int k = 0; k < 32; ++k) {
        unsigned e = e0 + k * 256u + t;
        if (e < N_EDGES) {
            unsigned r = (unsigned)erow[e];
            unsigned b = r >> 6;
            unsigned rank = atomicAdd(&hist[b], 1u);
            ebuf1[gbase[b] + rank] =
                make_uint2(((r & 63u) << 17) | (unsigned)ecol[e],
                           __float_as_uint(eval[e]));
        }
    }
}

// ---------------------------------------------------------------- bucket agg
// one block per coarse bucket (64 rows): counting-sort its slice by row in
// LDS, then wave-per-row register gather of fp16 y rows, write out fp32.
__global__ __launch_bounds__(256) void bucket_agg_kernel(
    const __half*   __restrict__ y,
    const unsigned* __restrict__ cstart,
    const uint2*    __restrict__ ebuf1,
    float*          __restrict__ out)
{
    __shared__ uint2    sorted[CAP];     // 16 KB
    __shared__ unsigned hist[BROWS];
    __shared__ unsigned sstart[BROWS];
    __shared__ unsigned scur[BROWS];

    const int t    = threadIdx.x;
    const int b    = blockIdx.x;                 // 1563 blocks
    const int lane = t & 63;
    const int wv   = t >> 6;
    const unsigned lo = cstart[b];
    const unsigned hi = cstart[b + 1];
    const unsigned n  = hi - lo;
    const unsigned nchunks = n ? (n + CAP - 1) / CAP : 1u;

    for (unsigned c = 0; c < nchunks; ++c) {
        const unsigned base = lo + c * CAP;
        const unsigned m = (base < hi) ? ((hi - base < CAP) ? hi - base : CAP) : 0u;

        if (t < BROWS) hist[t] = 0u;
        __syncthreads();

        for (unsigned i = t; i < m; i += 256)
            atomicAdd(&hist[ebuf1[base + i].x >> 17], 1u);
        __syncthreads();

        if (t < 64) {                            // scan 64 counters, wave 0
            unsigned v = hist[t];
            unsigned inc = v;
#pragma unroll
            for (int d = 1; d < 64; d <<= 1) {
                unsigned o = __shfl_up(inc, d);
                if (t >= d) inc += o;
            }
            unsigned excl = inc - v;
            sstart[t] = excl;
            scur[t]   = excl;
        }
        __syncthreads();

        for (unsigned i = t; i < m; i += 256) {
            uint2 rec = ebuf1[base + i];
            unsigned p = atomicAdd(&scur[rec.x >> 17], 1u);
            sorted[p] = rec;
        }
        __syncthreads();

        for (int r = wv; r < BROWS; r += 4) {
            int row = b * BROWS + r;
            if (row >= N_NODES) break;
            float ax, ay;
            if (c == 0) { ax = 0.f; ay = 0.f; }
            else {
                float2 p = *((const float2*)(out + (size_t)row * 128) + lane);
                ax = p.x; ay = p.y;
            }
            unsigned j = sstart[r], e = scur[r];
            for (; j + 4 <= e; j += 4) {
                uint2 r0 = sorted[j + 0];
                uint2 r1 = sorted[j + 1];
                uint2 r2 = sorted[j + 2];
                uint2 r3 = sorted[j + 3];
                const __half2 h0 = *((const __half2*)(y + (size_t)(r0.x & 0x1FFFFu) * 128) + lane);
                const __half2 h1 = *((const __half2*)(y + (size_t)(r1.x & 0x1FFFFu) * 128) + lane);
                const __half2 h2 = *((const __half2*)(y + (size_t)(r2.x & 0x1FFFFu) * 128) + lane);
                const __half2 h3 = *((const __half2*)(y + (size_t)(r3.x & 0x1FFFFu) * 128) + lane);
                float v0 = __uint_as_float(r0.y);
                float v1 = __uint_as_float(r1.y);
                float v2 = __uint_as_float(r2.y);
                float v3 = __uint_as_float(r3.y);
                float2 f0 = __half22float2(h0);
                float2 f1 = __half22float2(h1);
                float2 f2 = __half22float2(h2);
                float2 f3 = __half22float2(h3);
                ax = fmaf(f0.x, v0, ax); ay = fmaf(f0.y, v0, ay);
                ax = fmaf(f1.x, v1, ax); ay = fmaf(f1.y, v1, ay);
                ax = fmaf(f2.x, v2, ax); ay = fmaf(f2.y, v2, ay);
                ax = fmaf(f3.x, v3, ax); ay = fmaf(f3.y, v3, ay);
            }
            for (; j < e; ++j) {
                uint2 rr = sorted[j];
                const __half2 h = *((const __half2*)(y + (size_t)(rr.x & 0x1FFFFu) * 128) + lane);
                float v = __uint_as_float(rr.y);
                float2 f = __half22float2(h);
                ax = fmaf(f.x, v, ax); ay = fmaf(f.y, v, ay);
            }
            *((float2*)(out + (size_t)row * 128) + lane) = make_float2(ax, ay);
        }
        __syncthreads();
    }
}

// ---------------------------------------------------------------- launch
extern "C" void kernel_launch(void* const* d_in, const int* in_sizes, int n_in,
                              void* d_out, int out_size, void* d_ws, size_t ws_size,
                              hipStream_t stream) {
    const float* x    = (const float*)d_in[0];
    const int*   erow = (const int*)d_in[1];
    const int*   ecol = (const int*)d_in[2];
    const float* eval = (const float*)d_in[3];
    const float* W    = (const float*)d_in[4];
    float* out = (float*)d_out;

    char* ws = (char*)d_ws;
    __half*   y      = (__half*)  (ws);
    unsigned* ccnt   = (unsigned*)(ws + OFF_CCNT);
    unsigned* cstart = (unsigned*)(ws + OFF_CSTART);
    unsigned* ccur   = (unsigned*)(ws + OFF_CCUR);
    uint2*    ebuf1  = (uint2*)   (ws + OFF_EBUF1);

    gemm_xw_kernel<<<N_NODES / 32, 256, 0, stream>>>(x, W, y);
    zero_ccnt_kernel<<<(CB + 255) / 256, 256, 0, stream>>>(ccnt);
    coarse_hist_kernel<<<196, 256, 0, stream>>>(erow, ccnt);
    coarse_scan_kernel<<<1, 1024, 0, stream>>>(ccnt, cstart, ccur);
    partition_kernel<<<196, 256, 0, stream>>>(erow, ecol, eval, ccur, ebuf1);
    bucket_agg_kernel<<<CB, 256, 0, stream>>>(y, cstart, ebuf1, out);
}